// Round 2
// baseline (705.532 us; speedup 1.0000x reference)
//
#include <hip/hip_runtime.h>

#define NS 131072
#define KC 8

typedef unsigned long long u64;

// ---------------------------------------------------------------------------
// Kernel A: encoder -> z -> student-t q / argmax / counts.
// Block = 64 samples x 256 threads. thread = (sample s = t&63, quarter qw = t>>6).
// Wave w owns output quarter w => weight loads wave-uniform (scalar).
// LDS strides odd (129/65/17): bank = (odd*s + f) % 32 -> 2 lanes/bank = free.
// ---------------------------------------------------------------------------
__global__ __launch_bounds__(256) void k_enc(
    const float* __restrict__ x,
    const float* __restrict__ We1, const float* __restrict__ be1,
    const float* __restrict__ We2, const float* __restrict__ be2,
    const float* __restrict__ We3, const float* __restrict__ be3,
    const float* __restrict__ centers,
    float* __restrict__ out_z, float* __restrict__ out_q,
    int* __restrict__ cidx, int* __restrict__ counts)
{
    __shared__ float sm[64*129 + 64*17];   // 37376 B -> 4 blocks/CU
    float* xs = sm;                        // x staged [64][129]; later e overlay [64][65]
    float* zs = sm + 64*129;               // z staged [64][17]

    const int t  = threadIdx.x;
    const int s  = t & 63;
    const int qw = t >> 6;
    const int s0 = blockIdx.x * 64;

    // stage x (64 rows x 128 floats = 32KB) coalesced
    {
        const float4* xg = reinterpret_cast<const float4*>(x + (size_t)s0 * 128);
        #pragma unroll
        for (int c = 0; c < 8; ++c) {
            int i = t + c * 256;
            float4 v = xg[i];
            float* p = xs + (i >> 5) * 129 + (i & 31) * 4;
            p[0] = v.x; p[1] = v.y; p[2] = v.z; p[3] = v.w;
        }
    }
    __syncthreads();

    // ---- layer 1: 16 accums over 128 inputs ----
    float a[16];
    #pragma unroll
    for (int j = 0; j < 16; ++j) a[j] = be1[qw*16 + j];
    #pragma unroll 4
    for (int f = 0; f < 128; ++f) {
        float xv = xs[s*129 + f];
        const float* w = We1 + f*64 + qw*16;
        #pragma unroll
        for (int j = 0; j < 16; ++j) a[j] = fmaf(xv, w[j], a[j]);
    }
    #pragma unroll
    for (int j = 0; j < 16; ++j) a[j] = fmaxf(a[j], 0.f);
    __syncthreads();                       // all reads of xs done
    #pragma unroll
    for (int j = 0; j < 16; ++j) xs[s*65 + qw*16 + j] = a[j];   // e1 overlay
    __syncthreads();

    // ---- layer 2: 16 accums over 64 inputs ----
    float b[16];
    #pragma unroll
    for (int j = 0; j < 16; ++j) b[j] = be2[qw*16 + j];
    #pragma unroll 4
    for (int f = 0; f < 64; ++f) {
        float ev = xs[s*65 + f];
        const float* w = We2 + f*64 + qw*16;
        #pragma unroll
        for (int j = 0; j < 16; ++j) b[j] = fmaf(ev, w[j], b[j]);
    }
    #pragma unroll
    for (int j = 0; j < 16; ++j) b[j] = fmaxf(b[j], 0.f);
    __syncthreads();
    #pragma unroll
    for (int j = 0; j < 16; ++j) xs[s*65 + qw*16 + j] = b[j];   // e2 overlay
    __syncthreads();

    // ---- layer 3: 4 z-dims per thread over 64 inputs ----
    float z4[4];
    #pragma unroll
    for (int j = 0; j < 4; ++j) z4[j] = be3[qw*4 + j];
    #pragma unroll 4
    for (int f = 0; f < 64; ++f) {
        float ev = xs[s*65 + f];
        const float* w = We3 + f*16 + qw*4;
        #pragma unroll
        for (int j = 0; j < 4; ++j) z4[j] = fmaf(ev, w[j], z4[j]);
    }
    #pragma unroll
    for (int j = 0; j < 4; ++j) zs[s*17 + qw*4 + j] = z4[j];
    *reinterpret_cast<float4*>(out_z + (size_t)(s0 + s)*16 + qw*4) =
        make_float4(z4[0], z4[1], z4[2], z4[3]);
    __syncthreads();

    // ---- student-t + softmax + argmax (wave 0 only) ----
    if (qw == 0) {
        float zz[16];
        #pragma unroll
        for (int l = 0; l < 16; ++l) zz[l] = zs[s*17 + l];
        float d2[KC];
        #pragma unroll
        for (int k = 0; k < KC; ++k) {
            float acc = 0.f;
            #pragma unroll
            for (int l = 0; l < 16; ++l) {
                float dl = zz[l] - centers[k*16 + l];
                acc = fmaf(dl, dl, acc);
            }
            d2[k] = acc;
        }
        float lgt[KC], ex[KC];
        float m = -1e30f;
        #pragma unroll
        for (int k = 0; k < KC; ++k) { lgt[k] = -log1pf(d2[k]); m = fmaxf(m, lgt[k]); }
        float ssum = 0.f;
        #pragma unroll
        for (int k = 0; k < KC; ++k) { ex[k] = expf(lgt[k] - m); ssum += ex[k]; }
        float inv = 1.f / ssum;
        float4* oq = reinterpret_cast<float4*>(out_q + (size_t)(s0 + s)*8);
        oq[0] = make_float4(ex[0]*inv, ex[1]*inv, ex[2]*inv, ex[3]*inv);
        oq[1] = make_float4(ex[4]*inv, ex[5]*inv, ex[6]*inv, ex[7]*inv);
        int ci = 0; float best = d2[0];
        #pragma unroll
        for (int k = 1; k < KC; ++k) if (d2[k] < best) { best = d2[k]; ci = k; }
        cidx[s0 + s] = ci;
        #pragma unroll
        for (int k = 0; k < KC; ++k) {
            u64 mk = __ballot(ci == k);
            if (s == 0 && mk) atomicAdd(&counts[k], (int)__popcll(mk));
        }
    }
}

// ---------------------------------------------------------------------------
// Kernel B: exclusive scan of K=8 counts
// ---------------------------------------------------------------------------
__global__ void k_scan(const int* __restrict__ counts,
                       int* __restrict__ bases, int* __restrict__ cursors)
{
    if (threadIdx.x == 0) {
        int acc = 0;
        for (int k = 0; k < KC; ++k) {
            bases[k] = acc;
            cursors[k] = acc;
            acc += counts[k];
        }
    }
}

// ---------------------------------------------------------------------------
// Kernel C: counting-sort scatter (ballot-aggregated atomics)
// ---------------------------------------------------------------------------
__global__ __launch_bounds__(256) void k_scatter(
    const int* __restrict__ cidx, int* __restrict__ cursors, int* __restrict__ seg)
{
    const int s = blockIdx.x * 256 + threadIdx.x;
    const int lane = threadIdx.x & 63;
    const int ci = cidx[s];
    #pragma unroll
    for (int k = 0; k < KC; ++k) {
        u64 mk = __ballot(ci == k);
        if (ci == k) {
            const int leader = __ffsll(mk) - 1;
            int base = 0;
            if (lane == leader) base = atomicAdd(&cursors[k], (int)__popcll(mk));
            base = __shfl(base, leader, 64);
            const int pos = base + (int)__popcll(mk & (((u64)1 << lane) - 1));
            seg[pos] = s;
        }
    }
}

// ---------------------------------------------------------------------------
// Kernel D: routed survival heads + decoder + rec (x, z staged once in LDS).
// Block = (cluster k, chunk of 64 samples) x 256 threads; k block-uniform.
// ---------------------------------------------------------------------------
__global__ __launch_bounds__(256) void k_heads(
    const float* __restrict__ x, const float* __restrict__ zread,
    const float* __restrict__ Wd1, const float* __restrict__ bd1,
    const float* __restrict__ Wd2, const float* __restrict__ bd2,
    const float* __restrict__ Wh1, const float* __restrict__ bh1,
    const float* __restrict__ Wh2, const float* __restrict__ bh2,
    const int* __restrict__ counts, const int* __restrict__ bases,
    const int* __restrict__ seg,
    float* __restrict__ surv, float* __restrict__ xhat,
    float* __restrict__ rec, float* __restrict__ kld)
{
    __shared__ float sm[64*145 + 64*5];    // xz [64][145] (z cols 0..15, x cols 16..143) + rr
    __shared__ int idxs[64];
    float* xz = sm;
    float* rr = sm + 64*145;

    const int bq = blockIdx.x;
    int k = -1, chunk = 0, pref = 0;
    #pragma unroll
    for (int kk = 0; kk < KC; ++kk) {
        int ck = (counts[kk] + 63) >> 6;
        if (k < 0) {
            if (bq < pref + ck) { k = kk; chunk = bq - pref; }
            pref += ck;
        }
    }
    if (k < 0) return;                     // block-uniform: barrier-safe
    const int cnt = counts[k];
    const int t  = threadIdx.x;
    const int s  = t & 63;
    const int qw = t >> 6;
    const bool act = (chunk*64 + s) < cnt;

    if (t < 64) {
        int ii = chunk*64 + t;
        idxs[t] = seg[bases[k] + ((ii < cnt) ? ii : 0)];
    }
    __syncthreads();

    // stage z (cols 0..15) and x (cols 16..143)
    {
        int row = t >> 2, c4 = t & 3;
        float4 v = reinterpret_cast<const float4*>(zread + (size_t)idxs[row]*16)[c4];
        float* p = xz + row*145 + c4*4;
        p[0] = v.x; p[1] = v.y; p[2] = v.z; p[3] = v.w;
    }
    #pragma unroll
    for (int c = 0; c < 8; ++c) {
        int ii = t + c*256;
        int row = ii >> 5, c4 = ii & 31;
        float4 v = reinterpret_cast<const float4*>(x + (size_t)idxs[row]*128)[c4];
        float* p = xz + row*145 + 16 + c4*4;
        p[0] = v.x; p[1] = v.y; p[2] = v.z; p[3] = v.w;
    }
    __syncthreads();

    const int idx = idxs[s];

    // ---- decoder: d = relu(z Wd1 + bd1); xhat quarter + rec partial ----
    float d[16];
    #pragma unroll
    for (int j = 0; j < 16; ++j) d[j] = bd1[j];
    #pragma unroll
    for (int h = 0; h < 16; ++h) {
        float zv = xz[s*145 + h];
        const float* w = Wd1 + h*16;
        #pragma unroll
        for (int j = 0; j < 16; ++j) d[j] = fmaf(zv, w[j], d[j]);
    }
    #pragma unroll
    for (int j = 0; j < 16; ++j) d[j] = fmaxf(d[j], 0.f);

    float xh[32];
    #pragma unroll
    for (int j = 0; j < 32; ++j) xh[j] = bd2[qw*32 + j];
    #pragma unroll
    for (int h = 0; h < 16; ++h) {
        float dv = d[h];
        const float* w = Wd2 + h*128 + qw*32;
        #pragma unroll
        for (int j = 0; j < 32; ++j) xh[j] = fmaf(dv, w[j], xh[j]);
    }
    float rp = 0.f;
    #pragma unroll
    for (int j = 0; j < 32; ++j) {
        float df_ = xh[j] - xz[s*145 + 16 + qw*32 + j];
        rp = fmaf(df_, df_, rp);
    }
    rr[s*5 + qw] = rp;
    if (act) {
        float4* o4 = reinterpret_cast<float4*>(xhat + (size_t)idx*128 + qw*32);
        #pragma unroll
        for (int j = 0; j < 8; ++j)
            o4[j] = make_float4(xh[4*j], xh[4*j+1], xh[4*j+2], xh[4*j+3]);
    }
    __syncthreads();
    if (qw == 0 && act) {
        float rs = rr[s*5+0] + rr[s*5+1] + rr[s*5+2] + rr[s*5+3];
        rec[idx] = rs * (1.0f/128.0f);
        kld[idx] = 0.f;
    }

    // ---- head layer 1: 16 accums over 144 inputs [z,x] ----
    float a[16];
    #pragma unroll
    for (int j = 0; j < 16; ++j) a[j] = bh1[k*64 + qw*16 + j];
    #pragma unroll 4
    for (int f = 0; f < 144; ++f) {
        float hv = xz[s*145 + f];
        const float* w = Wh1 + ((size_t)k*144 + f)*64 + qw*16;
        #pragma unroll
        for (int j = 0; j < 16; ++j) a[j] = fmaf(hv, w[j], a[j]);
    }
    #pragma unroll
    for (int j = 0; j < 16; ++j) a[j] = fmaxf(a[j], 0.f);
    __syncthreads();                       // xz reads done
    #pragma unroll
    for (int j = 0; j < 16; ++j) xz[s*65 + qw*16 + j] = a[j];   // h1 overlay
    __syncthreads();

    // ---- head layer 2: quarters own {13,13,12,12} dims, bases {0,13,26,38} ----
    const int nd   = (qw < 2) ? 13 : 12;
    const int base = (qw < 2) ? qw*13 : 26 + (qw - 2)*12;
    float lg[13];
    #pragma unroll
    for (int j = 0; j < 13; ++j) lg[j] = bh2[k*50 + base + ((j < nd) ? j : 0)];
    #pragma unroll 4
    for (int h = 0; h < 64; ++h) {
        float hv = xz[s*65 + h];
        const float* w = Wh2 + ((size_t)k*64 + h)*50 + base;
        #pragma unroll
        for (int j = 0; j < 13; ++j) lg[j] = fmaf(hv, w[(j < nd) ? j : 0], lg[j]);
    }
    if (act) {
        float* so = surv + (size_t)idx*50 + base;
        #pragma unroll
        for (int j = 0; j < 13; ++j) if (j < nd) so[j] = lg[j];
    }
}

// ---------------------------------------------------------------------------
extern "C" void kernel_launch(void* const* d_in, const int* in_sizes, int n_in,
                              void* d_out, int out_size, void* d_ws, size_t ws_size,
                              hipStream_t stream)
{
    const float* x   = (const float*)d_in[0];
    const float* We1 = (const float*)d_in[1];
    const float* be1 = (const float*)d_in[2];
    const float* We2 = (const float*)d_in[3];
    const float* be2 = (const float*)d_in[4];
    const float* We3 = (const float*)d_in[5];
    const float* be3 = (const float*)d_in[6];
    const float* Wd1 = (const float*)d_in[7];
    const float* bd1 = (const float*)d_in[8];
    const float* Wd2 = (const float*)d_in[9];
    const float* bd2 = (const float*)d_in[10];
    const float* Wh1 = (const float*)d_in[11];
    const float* bh1 = (const float*)d_in[12];
    const float* Wh2 = (const float*)d_in[13];
    const float* bh2 = (const float*)d_in[14];
    const float* cen = (const float*)d_in[15];
    float* out = (float*)d_out;

    float* out_z  = out;
    float* out_q  = out + (size_t)NS * 16;
    float* out_sv = out + (size_t)NS * 24;
    float* out_xh = out + (size_t)NS * 74;
    float* out_rc = out + (size_t)NS * 202;
    float* out_kl = out + (size_t)NS * 203;

    int* cidx    = (int*)d_ws;       // [NS]
    int* counts  = cidx + NS;        // [8]
    int* bases   = counts + KC;      // [8]
    int* cursors = bases + KC;       // [8]
    int* seg     = cursors + KC;     // [NS]

    hipMemsetAsync(counts, 0, KC * sizeof(int), stream);

    k_enc<<<dim3(NS / 64), dim3(256), 0, stream>>>(
        x, We1, be1, We2, be2, We3, be3, cen, out_z, out_q, cidx, counts);

    k_scan<<<dim3(1), dim3(64), 0, stream>>>(counts, bases, cursors);

    k_scatter<<<dim3(NS / 256), dim3(256), 0, stream>>>(cidx, cursors, seg);

    k_heads<<<dim3(NS / 64 + KC), dim3(256), 0, stream>>>(
        x, out_z, Wd1, bd1, Wd2, bd2, Wh1, bh1, Wh2, bh2,
        counts, bases, seg, out_sv, out_xh, out_rc, out_kl);
}

// Round 3
// 579.724 us; speedup vs baseline: 1.2170x; 1.2170x over previous
//
#include <hip/hip_runtime.h>

#define NS 131072
#define KC 8

typedef unsigned long long u64;

// ---------------------------------------------------------------------------
// Kernel A: thread = sample. Encoder -> z -> q/argmax -> decoder -> xhat/rec.
// Weight addresses contain NO threadIdx terms -> compiler emits scalar
// s_load_dwordx16; weights feed v_fmac as SGPR operands (64 FMA per 16-dword
// load). x staged via LDS in 32-col chunks, stride 35 (gcd(3,32)=1 -> 2-way
// bank aliasing = free). Layer 2 in two 32-halves keeps live regs ~112.
// ---------------------------------------------------------------------------
__global__ __launch_bounds__(256, 2) void k_enc(
    const float* __restrict__ x,
    const float* __restrict__ We1, const float* __restrict__ be1,
    const float* __restrict__ We2, const float* __restrict__ be2,
    const float* __restrict__ We3, const float* __restrict__ be3,
    const float* __restrict__ Wd1, const float* __restrict__ bd1,
    const float* __restrict__ Wd2, const float* __restrict__ bd2,
    const float* __restrict__ centers,
    float* __restrict__ out_z, float* __restrict__ out_q,
    float* __restrict__ xhat, float* __restrict__ rec, float* __restrict__ kld,
    int* __restrict__ cidx, int* __restrict__ counts)
{
    __shared__ float xs[256 * 35];
    const int t  = threadIdx.x;
    const int s0 = blockIdx.x * 256;
    const int sg = s0 + t;

    // ---- layer 1: a1[64] over 128 inputs, x staged in 4 chunks of 32 ----
    float a1[64];
    #pragma unroll
    for (int j = 0; j < 64; ++j) a1[j] = be1[j];

    for (int c = 0; c < 4; ++c) {
        __syncthreads();
        #pragma unroll
        for (int r8 = 0; r8 < 8; ++r8) {
            const int row = (t >> 3) + r8 * 32;
            const int c4  = (t & 7) * 4;
            const float4 v = *reinterpret_cast<const float4*>(
                x + (size_t)(s0 + row) * 128 + c * 32 + c4);
            float* p = &xs[row * 35 + c4];
            p[0] = v.x; p[1] = v.y; p[2] = v.z; p[3] = v.w;
        }
        __syncthreads();
        #pragma unroll 2
        for (int f = 0; f < 32; ++f) {
            const float xv = xs[t * 35 + f];
            const float* w = We1 + (c * 32 + f) * 64;   // uniform -> s_load
            #pragma unroll
            for (int j = 0; j < 64; ++j) a1[j] = fmaf(xv, w[j], a1[j]);
        }
    }
    #pragma unroll
    for (int j = 0; j < 64; ++j) a1[j] = fmaxf(a1[j], 0.f);

    // ---- layer 2 (two 32-halves) + layer 3 interleaved: z[16] ----
    float z[16];
    #pragma unroll
    for (int l = 0; l < 16; ++l) z[l] = be3[l];
    #pragma unroll
    for (int half = 0; half < 2; ++half) {
        float b[32];
        #pragma unroll
        for (int j = 0; j < 32; ++j) b[j] = be2[half * 32 + j];
        #pragma unroll 2
        for (int h = 0; h < 64; ++h) {
            const float ev = a1[h];
            const float* w = We2 + h * 64 + half * 32;
            #pragma unroll
            for (int j = 0; j < 32; ++j) b[j] = fmaf(ev, w[j], b[j]);
        }
        #pragma unroll
        for (int j = 0; j < 32; ++j) b[j] = fmaxf(b[j], 0.f);
        #pragma unroll 4
        for (int h = 0; h < 32; ++h) {
            const float bv = b[h];
            const float* w = We3 + (half * 32 + h) * 16;
            #pragma unroll
            for (int l = 0; l < 16; ++l) z[l] = fmaf(bv, w[l], z[l]);
        }
    }

    // write z (64B contiguous per thread)
    {
        float4* oz = reinterpret_cast<float4*>(out_z + (size_t)sg * 16);
        oz[0] = make_float4(z[0],  z[1],  z[2],  z[3]);
        oz[1] = make_float4(z[4],  z[5],  z[6],  z[7]);
        oz[2] = make_float4(z[8],  z[9],  z[10], z[11]);
        oz[3] = make_float4(z[12], z[13], z[14], z[15]);
    }

    // ---- student-t + softmax + argmax + counts ----
    {
        float d2[KC];
        #pragma unroll
        for (int k = 0; k < KC; ++k) {
            float acc = 0.f;
            #pragma unroll
            for (int l = 0; l < 16; ++l) {
                const float dl = z[l] - centers[k * 16 + l];
                acc = fmaf(dl, dl, acc);
            }
            d2[k] = acc;
        }
        float lgt[KC], ex[KC];
        float m = -1e30f;
        #pragma unroll
        for (int k = 0; k < KC; ++k) { lgt[k] = -log1pf(d2[k]); m = fmaxf(m, lgt[k]); }
        float ssum = 0.f;
        #pragma unroll
        for (int k = 0; k < KC; ++k) { ex[k] = expf(lgt[k] - m); ssum += ex[k]; }
        const float inv = 1.f / ssum;
        float4* oq = reinterpret_cast<float4*>(out_q + (size_t)sg * 8);
        oq[0] = make_float4(ex[0] * inv, ex[1] * inv, ex[2] * inv, ex[3] * inv);
        oq[1] = make_float4(ex[4] * inv, ex[5] * inv, ex[6] * inv, ex[7] * inv);
        int ci = 0; float best = d2[0];
        #pragma unroll
        for (int k = 1; k < KC; ++k) if (d2[k] < best) { best = d2[k]; ci = k; }
        cidx[sg] = ci;
        #pragma unroll
        for (int k = 0; k < KC; ++k) {
            const u64 mk = __ballot(ci == k);
            if ((t & 63) == 0 && mk) atomicAdd(&counts[k], (int)__popcll(mk));
        }
    }

    // ---- decoder: d[16] = relu(z Wd1 + bd1) ----
    float d[16];
    #pragma unroll
    for (int j = 0; j < 16; ++j) d[j] = bd1[j];
    #pragma unroll 4
    for (int h = 0; h < 16; ++h) {
        const float zv = z[h];
        const float* w = Wd1 + h * 16;
        #pragma unroll
        for (int j = 0; j < 16; ++j) d[j] = fmaf(zv, w[j], d[j]);
    }
    #pragma unroll
    for (int j = 0; j < 16; ++j) d[j] = fmaxf(d[j], 0.f);

    // ---- xhat + rec, chunked; xhat bounced through LDS for coalesced stores
    float rec_acc = 0.f;
    for (int c = 0; c < 4; ++c) {
        __syncthreads();
        #pragma unroll
        for (int r8 = 0; r8 < 8; ++r8) {
            const int row = (t >> 3) + r8 * 32;
            const int c4  = (t & 7) * 4;
            const float4 v = *reinterpret_cast<const float4*>(
                x + (size_t)(s0 + row) * 128 + c * 32 + c4);
            float* p = &xs[row * 35 + c4];
            p[0] = v.x; p[1] = v.y; p[2] = v.z; p[3] = v.w;
        }
        __syncthreads();
        float xh[32];
        #pragma unroll
        for (int j = 0; j < 32; ++j) xh[j] = bd2[c * 32 + j];
        #pragma unroll 2
        for (int h = 0; h < 16; ++h) {
            const float dv = d[h];
            const float* w = Wd2 + h * 128 + c * 32;
            #pragma unroll
            for (int j = 0; j < 32; ++j) xh[j] = fmaf(dv, w[j], xh[j]);
        }
        #pragma unroll
        for (int j = 0; j < 32; ++j) {
            const float df_ = xh[j] - xs[t * 35 + j];
            rec_acc = fmaf(df_, df_, rec_acc);
        }
        __syncthreads();
        #pragma unroll
        for (int j = 0; j < 32; ++j) xs[t * 35 + j] = xh[j];
        __syncthreads();
        #pragma unroll
        for (int r8 = 0; r8 < 8; ++r8) {
            const int row = (t >> 3) + r8 * 32;
            const int c4  = (t & 7) * 4;
            const float* p = &xs[row * 35 + c4];
            *reinterpret_cast<float4*>(xhat + (size_t)(s0 + row) * 128 + c * 32 + c4) =
                make_float4(p[0], p[1], p[2], p[3]);
        }
    }
    rec[sg] = rec_acc * (1.f / 128.f);
    kld[sg] = 0.f;
}

// ---------------------------------------------------------------------------
// Kernel B: exclusive scan of K=8 counts
// ---------------------------------------------------------------------------
__global__ void k_scan(const int* __restrict__ counts,
                       int* __restrict__ bases, int* __restrict__ cursors)
{
    if (threadIdx.x == 0) {
        int acc = 0;
        for (int k = 0; k < KC; ++k) {
            bases[k] = acc;
            cursors[k] = acc;
            acc += counts[k];
        }
    }
}

// ---------------------------------------------------------------------------
// Kernel C: counting-sort scatter (ballot-aggregated atomics)
// ---------------------------------------------------------------------------
__global__ __launch_bounds__(256) void k_scatter(
    const int* __restrict__ cidx, int* __restrict__ cursors, int* __restrict__ seg)
{
    const int s = blockIdx.x * 256 + threadIdx.x;
    const int lane = threadIdx.x & 63;
    const int ci = cidx[s];
    #pragma unroll
    for (int k = 0; k < KC; ++k) {
        const u64 mk = __ballot(ci == k);
        if (ci == k) {
            const int leader = __ffsll(mk) - 1;
            int base = 0;
            if (lane == leader) base = atomicAdd(&cursors[k], (int)__popcll(mk));
            base = __shfl(base, leader, 64);
            const int pos = base + (int)__popcll(mk & (((u64)1 << lane) - 1));
            seg[pos] = s;
        }
    }
}

// ---------------------------------------------------------------------------
// Kernel D: routed heads. Thread = gathered sample; block-uniform cluster k
// forced to SGPR via readfirstlane -> all weight loads scalar. [z,x] staged
// via LDS in 5 passes (z 16 cols, then 4x32 x cols). Head L2 in two 25-col
// halves to bound registers.
// ---------------------------------------------------------------------------
__global__ __launch_bounds__(256, 2) void k_heads(
    const float* __restrict__ x, const float* __restrict__ zread,
    const float* __restrict__ Wh1, const float* __restrict__ bh1,
    const float* __restrict__ Wh2, const float* __restrict__ bh2,
    const int* __restrict__ counts, const int* __restrict__ bases,
    const int* __restrict__ seg,
    float* __restrict__ surv)
{
    __shared__ float xs[256 * 35];
    __shared__ int idxs[256];
    const int t = threadIdx.x;

    int k = -1, chunk = 0, pref = 0;
    #pragma unroll
    for (int kk = 0; kk < KC; ++kk) {
        const int ck = (counts[kk] + 255) >> 8;
        if (k < 0) {
            if ((int)blockIdx.x < pref + ck) { k = kk; chunk = (int)blockIdx.x - pref; }
            pref += ck;
        }
    }
    if (k < 0) return;                      // block-uniform, before any barrier
    k     = __builtin_amdgcn_readfirstlane(k);
    chunk = __builtin_amdgcn_readfirstlane(chunk);
    const int cnt  = __builtin_amdgcn_readfirstlane(counts[k]);
    const int base = __builtin_amdgcn_readfirstlane(bases[k]);

    const int i = chunk * 256 + t;
    const bool act = i < cnt;
    idxs[t] = seg[base + (act ? i : (cnt - 1))];
    __syncthreads();

    float a[64];
    #pragma unroll
    for (int j = 0; j < 64; ++j) a[j] = bh1[k * 64 + j];

    // ---- pass 0: z (16 cols) ----
    #pragma unroll
    for (int r4 = 0; r4 < 4; ++r4) {
        const int row = (t >> 2) + r4 * 64;
        const int c4  = (t & 3) * 4;
        const float4 v = *reinterpret_cast<const float4*>(
            zread + (size_t)idxs[row] * 16 + c4);
        float* p = &xs[row * 35 + c4];
        p[0] = v.x; p[1] = v.y; p[2] = v.z; p[3] = v.w;
    }
    __syncthreads();
    #pragma unroll 2
    for (int f = 0; f < 16; ++f) {
        const float hv = xs[t * 35 + f];
        const float* w = Wh1 + ((size_t)k * 144 + f) * 64;   // k in SGPR -> s_load
        #pragma unroll
        for (int j = 0; j < 64; ++j) a[j] = fmaf(hv, w[j], a[j]);
    }

    // ---- passes 1..4: x in 32-col chunks ----
    for (int c = 0; c < 4; ++c) {
        __syncthreads();
        #pragma unroll
        for (int r8 = 0; r8 < 8; ++r8) {
            const int row = (t >> 3) + r8 * 32;
            const int c4  = (t & 7) * 4;
            const float4 v = *reinterpret_cast<const float4*>(
                x + (size_t)idxs[row] * 128 + c * 32 + c4);
            float* p = &xs[row * 35 + c4];
            p[0] = v.x; p[1] = v.y; p[2] = v.z; p[3] = v.w;
        }
        __syncthreads();
        #pragma unroll 2
        for (int f = 0; f < 32; ++f) {
            const float hv = xs[t * 35 + f];
            const float* w = Wh1 + ((size_t)k * 144 + 16 + c * 32 + f) * 64;
            #pragma unroll
            for (int j = 0; j < 64; ++j) a[j] = fmaf(hv, w[j], a[j]);
        }
    }
    #pragma unroll
    for (int j = 0; j < 64; ++j) a[j] = fmaxf(a[j], 0.f);

    // ---- head layer 2: two halves of 25 outputs ----
    const int idx = idxs[t];
    #pragma unroll
    for (int half = 0; half < 2; ++half) {
        float lg[25];
        #pragma unroll
        for (int j = 0; j < 25; ++j) lg[j] = bh2[k * 50 + half * 25 + j];
        #pragma unroll 2
        for (int h = 0; h < 64; ++h) {
            const float av = a[h];
            const float* w = Wh2 + ((size_t)k * 64 + h) * 50 + half * 25;
            #pragma unroll
            for (int j = 0; j < 25; ++j) lg[j] = fmaf(av, w[j], lg[j]);
        }
        if (act) {
            float* so = surv + (size_t)idx * 50 + half * 25;
            #pragma unroll
            for (int j = 0; j < 25; ++j) so[j] = lg[j];
        }
    }
}

// ---------------------------------------------------------------------------
extern "C" void kernel_launch(void* const* d_in, const int* in_sizes, int n_in,
                              void* d_out, int out_size, void* d_ws, size_t ws_size,
                              hipStream_t stream)
{
    const float* x   = (const float*)d_in[0];
    const float* We1 = (const float*)d_in[1];
    const float* be1 = (const float*)d_in[2];
    const float* We2 = (const float*)d_in[3];
    const float* be2 = (const float*)d_in[4];
    const float* We3 = (const float*)d_in[5];
    const float* be3 = (const float*)d_in[6];
    const float* Wd1 = (const float*)d_in[7];
    const float* bd1 = (const float*)d_in[8];
    const float* Wd2 = (const float*)d_in[9];
    const float* bd2 = (const float*)d_in[10];
    const float* Wh1 = (const float*)d_in[11];
    const float* bh1 = (const float*)d_in[12];
    const float* Wh2 = (const float*)d_in[13];
    const float* bh2 = (const float*)d_in[14];
    const float* cen = (const float*)d_in[15];
    float* out = (float*)d_out;

    float* out_z  = out;
    float* out_q  = out + (size_t)NS * 16;
    float* out_sv = out + (size_t)NS * 24;
    float* out_xh = out + (size_t)NS * 74;
    float* out_rc = out + (size_t)NS * 202;
    float* out_kl = out + (size_t)NS * 203;

    int* cidx    = (int*)d_ws;       // [NS]
    int* counts  = cidx + NS;        // [8]
    int* bases   = counts + KC;      // [8]
    int* cursors = bases + KC;       // [8]
    int* seg     = cursors + KC;     // [NS]

    hipMemsetAsync(counts, 0, KC * sizeof(int), stream);

    k_enc<<<dim3(NS / 256), dim3(256), 0, stream>>>(
        x, We1, be1, We2, be2, We3, be3, Wd1, bd1, Wd2, bd2, cen,
        out_z, out_q, out_xh, out_rc, out_kl, cidx, counts);

    k_scan<<<dim3(1), dim3(64), 0, stream>>>(counts, bases, cursors);

    k_scatter<<<dim3(NS / 256), dim3(256), 0, stream>>>(cidx, cursors, seg);

    k_heads<<<dim3(NS / 256 + KC), dim3(256), 0, stream>>>(
        x, out_z, Wh1, bh1, Wh2, bh2, counts, bases, seg, out_sv);
}

// Round 4
// 524.036 us; speedup vs baseline: 1.3463x; 1.1063x over previous
//
#include <hip/hip_runtime.h>

#define NS 131072
#define KC 8

typedef unsigned long long u64;

// ---------------------------------------------------------------------------
// RULE: every index into a register array below is compile-time constant
// (fully-unrolled loops only). Anything needing a runtime index goes through
// LDS (xs, stride 35 -> bank = (3t+f)%32, conflict-free). Weight addresses
// contain no threadIdx -> scalar s_load, consumed as SGPR operand of v_fmac.
// ---------------------------------------------------------------------------

// ---------------------------------------------------------------------------
// Kernel A: thread = sample. Encoder -> z -> q/argmax -> decoder -> xhat/rec.
// ---------------------------------------------------------------------------
__global__ __launch_bounds__(256, 2) void k_enc(
    const float* __restrict__ x,
    const float* __restrict__ We1, const float* __restrict__ be1,
    const float* __restrict__ We2, const float* __restrict__ be2,
    const float* __restrict__ We3, const float* __restrict__ be3,
    const float* __restrict__ Wd1, const float* __restrict__ bd1,
    const float* __restrict__ Wd2, const float* __restrict__ bd2,
    const float* __restrict__ centers,
    float* __restrict__ out_z, float* __restrict__ out_q,
    float* __restrict__ xhat, float* __restrict__ rec, float* __restrict__ kld,
    int* __restrict__ cidx, int* __restrict__ counts)
{
    __shared__ float xs[256 * 35];
    const int t  = threadIdx.x;
    const int s0 = blockIdx.x * 256;
    const int sg = s0 + t;

    // ---- layer 1: a1[64] over 128 inputs; x staged in 4 chunks of 32 ----
    float a1[64];
    #pragma unroll
    for (int j = 0; j < 64; ++j) a1[j] = be1[j];

    for (int c = 0; c < 4; ++c) {
        __syncthreads();
        #pragma unroll
        for (int r8 = 0; r8 < 8; ++r8) {
            const int row = (t >> 3) + r8 * 32;
            const int c4  = (t & 7) * 4;
            const float4 v = *reinterpret_cast<const float4*>(
                x + (size_t)(s0 + row) * 128 + c * 32 + c4);
            float* p = &xs[row * 35 + c4];
            p[0] = v.x; p[1] = v.y; p[2] = v.z; p[3] = v.w;
        }
        __syncthreads();
        #pragma unroll 4
        for (int f = 0; f < 32; ++f) {            // f runtime: indexes LDS + uniform ptr only
            const float xv = xs[t * 35 + f];
            const float* w = We1 + (c * 32 + f) * 64;
            #pragma unroll
            for (int j = 0; j < 64; ++j) a1[j] = fmaf(xv, w[j], a1[j]);
        }
    }
    #pragma unroll
    for (int j = 0; j < 64; ++j) a1[j] = fmaxf(a1[j], 0.f);

    // ---- layer 2: b[64]; a1 consumed via LDS in two 32-chunks ----
    float b[64];
    #pragma unroll
    for (int j = 0; j < 64; ++j) b[j] = be2[j];
    #pragma unroll
    for (int h2 = 0; h2 < 2; ++h2) {              // h2 static (full unroll)
        __syncthreads();
        #pragma unroll
        for (int j = 0; j < 32; ++j) xs[t * 35 + j] = a1[h2 * 32 + j];
        __syncthreads();
        #pragma unroll 4
        for (int f = 0; f < 32; ++f) {
            const float ev = xs[t * 35 + f];
            const float* w = We2 + (h2 * 32 + f) * 64;
            #pragma unroll
            for (int j = 0; j < 64; ++j) b[j] = fmaf(ev, w[j], b[j]);
        }
    }
    #pragma unroll
    for (int j = 0; j < 64; ++j) b[j] = fmaxf(b[j], 0.f);

    // ---- layer 3: z[16]; b consumed via LDS in two 32-chunks ----
    float z[16];
    #pragma unroll
    for (int l = 0; l < 16; ++l) z[l] = be3[l];
    #pragma unroll
    for (int h2 = 0; h2 < 2; ++h2) {
        __syncthreads();
        #pragma unroll
        for (int j = 0; j < 32; ++j) xs[t * 35 + j] = b[h2 * 32 + j];
        __syncthreads();
        #pragma unroll 4
        for (int f = 0; f < 32; ++f) {
            const float bv = xs[t * 35 + f];
            const float* w = We3 + (h2 * 32 + f) * 16;
            #pragma unroll
            for (int l = 0; l < 16; ++l) z[l] = fmaf(bv, w[l], z[l]);
        }
    }

    // write z
    {
        float4* oz = reinterpret_cast<float4*>(out_z + (size_t)sg * 16);
        oz[0] = make_float4(z[0],  z[1],  z[2],  z[3]);
        oz[1] = make_float4(z[4],  z[5],  z[6],  z[7]);
        oz[2] = make_float4(z[8],  z[9],  z[10], z[11]);
        oz[3] = make_float4(z[12], z[13], z[14], z[15]);
    }

    // ---- student-t + softmax + argmax + counts (all loops fully unrolled) --
    {
        float d2[KC];
        #pragma unroll
        for (int k = 0; k < KC; ++k) {
            float acc = 0.f;
            #pragma unroll
            for (int l = 0; l < 16; ++l) {
                const float dl = z[l] - centers[k * 16 + l];
                acc = fmaf(dl, dl, acc);
            }
            d2[k] = acc;
        }
        float lgt[KC], ex[KC];
        float m = -1e30f;
        #pragma unroll
        for (int k = 0; k < KC; ++k) { lgt[k] = -log1pf(d2[k]); m = fmaxf(m, lgt[k]); }
        float ssum = 0.f;
        #pragma unroll
        for (int k = 0; k < KC; ++k) { ex[k] = expf(lgt[k] - m); ssum += ex[k]; }
        const float inv = 1.f / ssum;
        float4* oq = reinterpret_cast<float4*>(out_q + (size_t)sg * 8);
        oq[0] = make_float4(ex[0] * inv, ex[1] * inv, ex[2] * inv, ex[3] * inv);
        oq[1] = make_float4(ex[4] * inv, ex[5] * inv, ex[6] * inv, ex[7] * inv);
        int ci = 0; float best = d2[0];
        #pragma unroll
        for (int k = 1; k < KC; ++k) if (d2[k] < best) { best = d2[k]; ci = k; }
        cidx[sg] = ci;
        #pragma unroll
        for (int k = 0; k < KC; ++k) {
            const u64 mk = __ballot(ci == k);
            if ((t & 63) == 0 && mk) atomicAdd(&counts[k], (int)__popcll(mk));
        }
    }

    // ---- decoder: d[16] (h fully unrolled -> z[h] static) ----
    float d[16];
    #pragma unroll
    for (int j = 0; j < 16; ++j) d[j] = bd1[j];
    #pragma unroll
    for (int h = 0; h < 16; ++h) {
        const float zv = z[h];
        const float* w = Wd1 + h * 16;
        #pragma unroll
        for (int j = 0; j < 16; ++j) d[j] = fmaf(zv, w[j], d[j]);
    }
    #pragma unroll
    for (int j = 0; j < 16; ++j) d[j] = fmaxf(d[j], 0.f);

    // ---- xhat + rec in 4 chunks of 32 cols; stores bounced via LDS ----
    float rec_acc = 0.f;
    for (int c = 0; c < 4; ++c) {
        __syncthreads();
        #pragma unroll
        for (int r8 = 0; r8 < 8; ++r8) {
            const int row = (t >> 3) + r8 * 32;
            const int c4  = (t & 7) * 4;
            const float4 v = *reinterpret_cast<const float4*>(
                x + (size_t)(s0 + row) * 128 + c * 32 + c4);
            float* p = &xs[row * 35 + c4];
            p[0] = v.x; p[1] = v.y; p[2] = v.z; p[3] = v.w;
        }
        __syncthreads();
        float xh[32];
        #pragma unroll
        for (int j = 0; j < 32; ++j) xh[j] = bd2[c * 32 + j];
        #pragma unroll
        for (int h = 0; h < 16; ++h) {            // full unroll -> d[h] static
            const float dv = d[h];
            const float* w = Wd2 + h * 128 + c * 32;
            #pragma unroll
            for (int j = 0; j < 32; ++j) xh[j] = fmaf(dv, w[j], xh[j]);
        }
        #pragma unroll
        for (int j = 0; j < 32; ++j) {
            const float df_ = xh[j] - xs[t * 35 + j];
            rec_acc = fmaf(df_, df_, rec_acc);
        }
        __syncthreads();
        #pragma unroll
        for (int j = 0; j < 32; ++j) xs[t * 35 + j] = xh[j];
        __syncthreads();
        #pragma unroll
        for (int r8 = 0; r8 < 8; ++r8) {
            const int row = (t >> 3) + r8 * 32;
            const int c4  = (t & 7) * 4;
            const float* p = &xs[row * 35 + c4];
            *reinterpret_cast<float4*>(xhat + (size_t)(s0 + row) * 128 + c * 32 + c4) =
                make_float4(p[0], p[1], p[2], p[3]);
        }
    }
    rec[sg] = rec_acc * (1.f / 128.f);
    kld[sg] = 0.f;
}

// ---------------------------------------------------------------------------
// Kernel B: exclusive scan of K=8 counts
// ---------------------------------------------------------------------------
__global__ void k_scan(const int* __restrict__ counts,
                       int* __restrict__ bases, int* __restrict__ cursors)
{
    if (threadIdx.x == 0) {
        int acc = 0;
        for (int k = 0; k < KC; ++k) {
            bases[k] = acc;
            cursors[k] = acc;
            acc += counts[k];
        }
    }
}

// ---------------------------------------------------------------------------
// Kernel C: counting-sort scatter (ballot-aggregated atomics)
// ---------------------------------------------------------------------------
__global__ __launch_bounds__(256) void k_scatter(
    const int* __restrict__ cidx, int* __restrict__ cursors, int* __restrict__ seg)
{
    const int s = blockIdx.x * 256 + threadIdx.x;
    const int lane = threadIdx.x & 63;
    const int ci = cidx[s];
    #pragma unroll
    for (int k = 0; k < KC; ++k) {
        const u64 mk = __ballot(ci == k);
        if (ci == k) {
            const int leader = __ffsll(mk) - 1;
            int base = 0;
            if (lane == leader) base = atomicAdd(&cursors[k], (int)__popcll(mk));
            base = __shfl(base, leader, 64);
            const int pos = base + (int)__popcll(mk & (((u64)1 << lane) - 1));
            seg[pos] = s;
        }
    }
}

// ---------------------------------------------------------------------------
// Kernel D: routed heads. Cluster k block-uniform (SGPR via readfirstlane).
// a[64] only statically indexed; head-L2 consumes a via LDS chunks.
// ---------------------------------------------------------------------------
__global__ __launch_bounds__(256, 2) void k_heads(
    const float* __restrict__ x, const float* __restrict__ zread,
    const float* __restrict__ Wh1, const float* __restrict__ bh1,
    const float* __restrict__ Wh2, const float* __restrict__ bh2,
    const int* __restrict__ counts, const int* __restrict__ bases,
    const int* __restrict__ seg,
    float* __restrict__ surv)
{
    __shared__ float xs[256 * 35];
    __shared__ int idxs[256];
    const int t = threadIdx.x;

    int k = -1, chunk = 0, pref = 0;
    #pragma unroll
    for (int kk = 0; kk < KC; ++kk) {
        const int ck = (counts[kk] + 255) >> 8;
        if (k < 0) {
            if ((int)blockIdx.x < pref + ck) { k = kk; chunk = (int)blockIdx.x - pref; }
            pref += ck;
        }
    }
    if (k < 0) return;                      // block-uniform, before any barrier
    k     = __builtin_amdgcn_readfirstlane(k);
    chunk = __builtin_amdgcn_readfirstlane(chunk);
    const int cnt  = __builtin_amdgcn_readfirstlane(counts[k]);
    const int base = __builtin_amdgcn_readfirstlane(bases[k]);

    const int i = chunk * 256 + t;
    const bool act = i < cnt;
    idxs[t] = seg[base + (act ? i : (cnt - 1))];
    __syncthreads();

    float a[64];
    #pragma unroll
    for (int j = 0; j < 64; ++j) a[j] = bh1[k * 64 + j];

    // ---- pass 0: z (16 cols) ----
    #pragma unroll
    for (int r4 = 0; r4 < 4; ++r4) {
        const int row = (t >> 2) + r4 * 64;
        const int c4  = (t & 3) * 4;
        const float4 v = *reinterpret_cast<const float4*>(
            zread + (size_t)idxs[row] * 16 + c4);
        float* p = &xs[row * 35 + c4];
        p[0] = v.x; p[1] = v.y; p[2] = v.z; p[3] = v.w;
    }
    __syncthreads();
    #pragma unroll 4
    for (int f = 0; f < 16; ++f) {
        const float hv = xs[t * 35 + f];
        const float* w = Wh1 + ((size_t)k * 144 + f) * 64;
        #pragma unroll
        for (int j = 0; j < 64; ++j) a[j] = fmaf(hv, w[j], a[j]);
    }

    // ---- passes 1..4: x in 32-col chunks ----
    for (int c = 0; c < 4; ++c) {
        __syncthreads();
        #pragma unroll
        for (int r8 = 0; r8 < 8; ++r8) {
            const int row = (t >> 3) + r8 * 32;
            const int c4  = (t & 7) * 4;
            const float4 v = *reinterpret_cast<const float4*>(
                x + (size_t)idxs[row] * 128 + c * 32 + c4);
            float* p = &xs[row * 35 + c4];
            p[0] = v.x; p[1] = v.y; p[2] = v.z; p[3] = v.w;
        }
        __syncthreads();
        #pragma unroll 4
        for (int f = 0; f < 32; ++f) {
            const float hv = xs[t * 35 + f];
            const float* w = Wh1 + ((size_t)k * 144 + 16 + c * 32 + f) * 64;
            #pragma unroll
            for (int j = 0; j < 64; ++j) a[j] = fmaf(hv, w[j], a[j]);
        }
    }
    #pragma unroll
    for (int j = 0; j < 64; ++j) a[j] = fmaxf(a[j], 0.f);

    // ---- head layer 2: lg[50]; a consumed via LDS in two 32-chunks ----
    float lg[50];
    #pragma unroll
    for (int j = 0; j < 50; ++j) lg[j] = bh2[k * 50 + j];
    #pragma unroll
    for (int h2 = 0; h2 < 2; ++h2) {
        __syncthreads();
        #pragma unroll
        for (int j = 0; j < 32; ++j) xs[t * 35 + j] = a[h2 * 32 + j];
        __syncthreads();
        #pragma unroll 2
        for (int f = 0; f < 32; ++f) {
            const float av = xs[t * 35 + f];
            const float* w = Wh2 + ((size_t)k * 64 + h2 * 32 + f) * 50;
            #pragma unroll
            for (int j = 0; j < 50; ++j) lg[j] = fmaf(av, w[j], lg[j]);
        }
    }

    if (act) {
        const int idx = idxs[t];
        float* so = surv + (size_t)idx * 50;
        #pragma unroll
        for (int j = 0; j < 50; ++j) so[j] = lg[j];
    }
}

// ---------------------------------------------------------------------------
extern "C" void kernel_launch(void* const* d_in, const int* in_sizes, int n_in,
                              void* d_out, int out_size, void* d_ws, size_t ws_size,
                              hipStream_t stream)
{
    const float* x   = (const float*)d_in[0];
    const float* We1 = (const float*)d_in[1];
    const float* be1 = (const float*)d_in[2];
    const float* We2 = (const float*)d_in[3];
    const float* be2 = (const float*)d_in[4];
    const float* We3 = (const float*)d_in[5];
    const float* be3 = (const float*)d_in[6];
    const float* Wd1 = (const float*)d_in[7];
    const float* bd1 = (const float*)d_in[8];
    const float* Wd2 = (const float*)d_in[9];
    const float* bd2 = (const float*)d_in[10];
    const float* Wh1 = (const float*)d_in[11];
    const float* bh1 = (const float*)d_in[12];
    const float* Wh2 = (const float*)d_in[13];
    const float* bh2 = (const float*)d_in[14];
    const float* cen = (const float*)d_in[15];
    float* out = (float*)d_out;

    float* out_z  = out;
    float* out_q  = out + (size_t)NS * 16;
    float* out_sv = out + (size_t)NS * 24;
    float* out_xh = out + (size_t)NS * 74;
    float* out_rc = out + (size_t)NS * 202;
    float* out_kl = out + (size_t)NS * 203;

    int* cidx    = (int*)d_ws;       // [NS]
    int* counts  = cidx + NS;        // [8]
    int* bases   = counts + KC;      // [8]
    int* cursors = bases + KC;       // [8]
    int* seg     = cursors + KC;     // [NS]

    hipMemsetAsync(counts, 0, KC * sizeof(int), stream);

    k_enc<<<dim3(NS / 256), dim3(256), 0, stream>>>(
        x, We1, be1, We2, be2, We3, be3, Wd1, bd1, Wd2, bd2, cen,
        out_z, out_q, out_xh, out_rc, out_kl, cidx, counts);

    k_scan<<<dim3(1), dim3(64), 0, stream>>>(counts, bases, cursors);

    k_scatter<<<dim3(NS / 256), dim3(256), 0, stream>>>(cidx, cursors, seg);

    k_heads<<<dim3(NS / 256 + KC), dim3(256), 0, stream>>>(
        x, out_z, Wh1, bh1, Wh2, bh2, counts, bases, seg, out_sv);
}

// Round 5
// 454.696 us; speedup vs baseline: 1.5517x; 1.1525x over previous
//
#include <hip/hip_runtime.h>

#define NS 131072
#define KC 8
typedef unsigned long long u64;

#define LD4(idx) (*reinterpret_cast<const float4*>(&sm[(idx)]))
#define ST4(idx) (*reinterpret_cast<float4*>(&sm[(idx)]))

#define FMA_ROW(ACC, A, W0, W1) do { \
  ACC[0]=fmaf((A),(W0).x,ACC[0]); ACC[1]=fmaf((A),(W0).y,ACC[1]); \
  ACC[2]=fmaf((A),(W0).z,ACC[2]); ACC[3]=fmaf((A),(W0).w,ACC[3]); \
  ACC[4]=fmaf((A),(W1).x,ACC[4]); ACC[5]=fmaf((A),(W1).y,ACC[5]); \
  ACC[6]=fmaf((A),(W1).z,ACC[6]); ACC[7]=fmaf((A),(W1).w,ACC[7]); } while(0)

// One 4-wide K step: A = 2 samples (b128 each), B = 4 k-rows x 8 outputs
// (2 b128 per row, broadcast across st-lanes). 64 FMAs, all static indices.
#define K4STEP(kc, ABASE, ASTR, BBASE, BSTR, JOFF) do { \
  const float4 a0 = LD4((ABASE) + (2*st+0)*(ASTR) + (kc)*4); \
  const float4 a1 = LD4((ABASE) + (2*st+1)*(ASTR) + (kc)*4); \
  const float4 w0a = LD4((BBASE) + ((kc)*4+0)*(BSTR) + (JOFF)); \
  const float4 w0b = LD4((BBASE) + ((kc)*4+0)*(BSTR) + (JOFF)+4); \
  const float4 w1a = LD4((BBASE) + ((kc)*4+1)*(BSTR) + (JOFF)); \
  const float4 w1b = LD4((BBASE) + ((kc)*4+1)*(BSTR) + (JOFF)+4); \
  const float4 w2a = LD4((BBASE) + ((kc)*4+2)*(BSTR) + (JOFF)); \
  const float4 w2b = LD4((BBASE) + ((kc)*4+2)*(BSTR) + (JOFF)+4); \
  const float4 w3a = LD4((BBASE) + ((kc)*4+3)*(BSTR) + (JOFF)); \
  const float4 w3b = LD4((BBASE) + ((kc)*4+3)*(BSTR) + (JOFF)+4); \
  FMA_ROW(acc0, a0.x, w0a, w0b); FMA_ROW(acc1, a1.x, w0a, w0b); \
  FMA_ROW(acc0, a0.y, w1a, w1b); FMA_ROW(acc1, a1.y, w1a, w1b); \
  FMA_ROW(acc0, a0.z, w2a, w2b); FMA_ROW(acc1, a1.z, w2a, w2b); \
  FMA_ROW(acc0, a0.w, w3a, w3b); FMA_ROW(acc1, a1.w, w3a, w3b); \
} while(0)

#define ACC_DECL_INIT(BPTR, JO) \
  float acc0[8], acc1[8]; \
  { const float4 u = *reinterpret_cast<const float4*>(&(BPTR)[(JO)]); \
    const float4 v = *reinterpret_cast<const float4*>(&(BPTR)[(JO)+4]); \
    acc0[0]=u.x; acc0[1]=u.y; acc0[2]=u.z; acc0[3]=u.w; \
    acc0[4]=v.x; acc0[5]=v.y; acc0[6]=v.z; acc0[7]=v.w; \
    acc1[0]=u.x; acc1[1]=u.y; acc1[2]=u.z; acc1[3]=u.w; \
    acc1[4]=v.x; acc1[5]=v.y; acc1[6]=v.z; acc1[7]=v.w; }

#define RELU16() do { _Pragma("unroll") \
  for (int j_ = 0; j_ < 8; ++j_) { acc0[j_]=fmaxf(acc0[j_],0.f); acc1[j_]=fmaxf(acc1[j_],0.f); } } while(0)

#define STORE_LDS_ROWS(BASE, STR, JO) do { \
  ST4((BASE)+(2*st+0)*(STR)+(JO))   = make_float4(acc0[0],acc0[1],acc0[2],acc0[3]); \
  ST4((BASE)+(2*st+0)*(STR)+(JO)+4) = make_float4(acc0[4],acc0[5],acc0[6],acc0[7]); \
  ST4((BASE)+(2*st+1)*(STR)+(JO))   = make_float4(acc1[0],acc1[1],acc1[2],acc1[3]); \
  ST4((BASE)+(2*st+1)*(STR)+(JO)+4) = make_float4(acc1[4],acc1[5],acc1[6],acc1[7]); } while(0)

// k_enc arena (words): XC[0,2304) x-chunk [64][36] (later z [64][20]);
// WE[2304,4352) weight chunk; E1[4352,8704) [64][68] (later d [64][20]);
// E2[8704,13056) [64][68].  Total 52224 B -> 3 blocks/CU.
#define XC 0
#define WE 2304
#define E1 4352
#define E2 8704

__global__ __launch_bounds__(256, 3) void k_enc(
    const float* __restrict__ x,
    const float* __restrict__ We1, const float* __restrict__ be1,
    const float* __restrict__ We2, const float* __restrict__ be2,
    const float* __restrict__ We3, const float* __restrict__ be3,
    const float* __restrict__ Wd1, const float* __restrict__ bd1,
    const float* __restrict__ Wd2, const float* __restrict__ bd2,
    const float* __restrict__ centers,
    float* __restrict__ out_z, float* __restrict__ out_q,
    float* __restrict__ xhat, float* __restrict__ rec, float* __restrict__ kld,
    int* __restrict__ cidx, int* __restrict__ counts)
{
    __shared__ float sm[13056];
    const int t  = threadIdx.x;
    const int ot = t & 7;           // output-group (8 outputs)
    const int st = t >> 3;          // sample-group (2 samples), 0..31
    const int job = ot * 8;
    const int s0 = blockIdx.x * 64;

    // ================= layer 1: K=128 in 4 chunks of 32 =================
    ACC_DECL_INIT(be1, job);
    for (int c = 0; c < 4; ++c) {
        __syncthreads();
        #pragma unroll
        for (int p = 0; p < 2; ++p) {       // x chunk [64][32]
            const int g = p * 256 + t, row = g >> 3, c4 = g & 7;
            ST4(XC + row*36 + c4*4) = *reinterpret_cast<const float4*>(
                &x[(size_t)(s0 + row)*128 + c*32 + c4*4]);
        }
        #pragma unroll
        for (int p = 0; p < 2; ++p) {       // We1 rows c*32..+31
            const int g = p * 256 + t, row = g >> 4, c4 = g & 15;
            ST4(WE + row*64 + c4*4) = *reinterpret_cast<const float4*>(
                &We1[(size_t)(c*32 + row)*64 + c4*4]);
        }
        __syncthreads();
        #pragma unroll 2
        for (int kc = 0; kc < 8; ++kc) K4STEP(kc, XC, 36, WE, 64, job);
    }
    RELU16();
    STORE_LDS_ROWS(E1, 68, job);
    // ================= layer 2: K=64 in 2 chunks of 32 =================
    {
        ACC_DECL_INIT(be2, job);
        #pragma unroll
        for (int c = 0; c < 2; ++c) {
            __syncthreads();
            #pragma unroll
            for (int p = 0; p < 2; ++p) {
                const int g = p * 256 + t, row = g >> 4, c4 = g & 15;
                ST4(WE + row*64 + c4*4) = *reinterpret_cast<const float4*>(
                    &We2[(size_t)(c*32 + row)*64 + c4*4]);
            }
            __syncthreads();
            #pragma unroll 2
            for (int kc = 0; kc < 8; ++kc) K4STEP(kc, E1 + c*32, 68, WE, 64, job);
        }
        RELU16();
        STORE_LDS_ROWS(E2, 68, job);
    }
    // ================= layer 3: K=64, N=16 (ot<2) =================
    __syncthreads();
    {   // stage We3 [64][16]
        const int row = t >> 2, c4 = t & 3;
        ST4(WE + row*16 + c4*4) = *reinterpret_cast<const float4*>(
            &We3[(size_t)row*16 + c4*4]);
    }
    __syncthreads();
    if (ot < 2) {
        ACC_DECL_INIT(be3, job);
        #pragma unroll 2
        for (int kc = 0; kc < 16; ++kc) K4STEP(kc, E2, 68, WE, 16, job);
        STORE_LDS_ROWS(XC, 20, job);        // z overlay in XC
    }
    __syncthreads();

    // ======== z write + student-t/q/argmax/counts (wave 0) ========
    if (t < 64) {
        float zz[16];
        #pragma unroll
        for (int l = 0; l < 16; ++l) zz[l] = sm[XC + t*20 + l];
        float4* oz = reinterpret_cast<float4*>(out_z + (size_t)(s0 + t)*16);
        oz[0] = make_float4(zz[0],zz[1],zz[2],zz[3]);
        oz[1] = make_float4(zz[4],zz[5],zz[6],zz[7]);
        oz[2] = make_float4(zz[8],zz[9],zz[10],zz[11]);
        oz[3] = make_float4(zz[12],zz[13],zz[14],zz[15]);
        float d2[KC];
        #pragma unroll
        for (int k = 0; k < KC; ++k) {
            float acc = 0.f;
            #pragma unroll
            for (int l = 0; l < 16; ++l) {
                const float dl = zz[l] - centers[k*16 + l];
                acc = fmaf(dl, dl, acc);
            }
            d2[k] = acc;
        }
        float lgt[KC], ex[KC];
        float m = -1e30f;
        #pragma unroll
        for (int k = 0; k < KC; ++k) { lgt[k] = -log1pf(d2[k]); m = fmaxf(m, lgt[k]); }
        float ssum = 0.f;
        #pragma unroll
        for (int k = 0; k < KC; ++k) { ex[k] = expf(lgt[k] - m); ssum += ex[k]; }
        const float inv = 1.f / ssum;
        float4* oq = reinterpret_cast<float4*>(out_q + (size_t)(s0 + t)*8);
        oq[0] = make_float4(ex[0]*inv, ex[1]*inv, ex[2]*inv, ex[3]*inv);
        oq[1] = make_float4(ex[4]*inv, ex[5]*inv, ex[6]*inv, ex[7]*inv);
        int ci = 0; float best = d2[0];
        #pragma unroll
        for (int k = 1; k < KC; ++k) if (d2[k] < best) { best = d2[k]; ci = k; }
        cidx[s0 + t] = ci;
        #pragma unroll
        for (int k = 0; k < KC; ++k) {
            const u64 mk = __ballot(ci == k);
            if (t == 0 && mk) atomicAdd(&counts[k], (int)__popcll(mk));
        }
        kld[s0 + t] = 0.f;
    }
    // ================= decoder d: K=16, N=16 (ot<2) =================
    __syncthreads();
    if (t < 64) {   // stage Wd1 [16][16]
        const int row = t >> 2, c4 = t & 3;
        ST4(WE + row*16 + c4*4) = *reinterpret_cast<const float4*>(
            &Wd1[(size_t)row*16 + c4*4]);
    }
    __syncthreads();
    if (ot < 2) {
        ACC_DECL_INIT(bd1, job);
        #pragma unroll
        for (int kc = 0; kc < 4; ++kc) K4STEP(kc, XC, 20, WE, 16, job);
        RELU16();
        STORE_LDS_ROWS(E1, 20, job);        // d overlay in E1
    }
    __syncthreads();
    // ================= xhat: K=16, N=128 (2 halves) + rec =================
    #pragma unroll
    for (int p = 0; p < 2; ++p) {           // stage Wd2 [16][128]
        const int g = p * 256 + t, row = g >> 5, c4 = g & 31;
        ST4(WE + row*128 + c4*4) = *reinterpret_cast<const float4*>(
            &Wd2[(size_t)row*128 + c4*4]);
    }
    __syncthreads();
    float rp0 = 0.f, rp1 = 0.f;
    #pragma unroll
    for (int h = 0; h < 2; ++h) {
        ACC_DECL_INIT(bd2, h*64 + job);
        #pragma unroll
        for (int kc = 0; kc < 4; ++kc) K4STEP(kc, E1, 20, WE, 128, h*64 + job);
        const float4 xa0 = *reinterpret_cast<const float4*>(&x[(size_t)(s0+2*st+0)*128 + h*64 + job]);
        const float4 xa1 = *reinterpret_cast<const float4*>(&x[(size_t)(s0+2*st+0)*128 + h*64 + job + 4]);
        const float4 xb0 = *reinterpret_cast<const float4*>(&x[(size_t)(s0+2*st+1)*128 + h*64 + job]);
        const float4 xb1 = *reinterpret_cast<const float4*>(&x[(size_t)(s0+2*st+1)*128 + h*64 + job + 4]);
        float dfv;
        dfv = acc0[0]-xa0.x; rp0 = fmaf(dfv,dfv,rp0);
        dfv = acc0[1]-xa0.y; rp0 = fmaf(dfv,dfv,rp0);
        dfv = acc0[2]-xa0.z; rp0 = fmaf(dfv,dfv,rp0);
        dfv = acc0[3]-xa0.w; rp0 = fmaf(dfv,dfv,rp0);
        dfv = acc0[4]-xa1.x; rp0 = fmaf(dfv,dfv,rp0);
        dfv = acc0[5]-xa1.y; rp0 = fmaf(dfv,dfv,rp0);
        dfv = acc0[6]-xa1.z; rp0 = fmaf(dfv,dfv,rp0);
        dfv = acc0[7]-xa1.w; rp0 = fmaf(dfv,dfv,rp0);
        dfv = acc1[0]-xb0.x; rp1 = fmaf(dfv,dfv,rp1);
        dfv = acc1[1]-xb0.y; rp1 = fmaf(dfv,dfv,rp1);
        dfv = acc1[2]-xb0.z; rp1 = fmaf(dfv,dfv,rp1);
        dfv = acc1[3]-xb0.w; rp1 = fmaf(dfv,dfv,rp1);
        dfv = acc1[4]-xb1.x; rp1 = fmaf(dfv,dfv,rp1);
        dfv = acc1[5]-xb1.y; rp1 = fmaf(dfv,dfv,rp1);
        dfv = acc1[6]-xb1.z; rp1 = fmaf(dfv,dfv,rp1);
        dfv = acc1[7]-xb1.w; rp1 = fmaf(dfv,dfv,rp1);
        float4* o;
        o = reinterpret_cast<float4*>(xhat + (size_t)(s0+2*st+0)*128 + h*64 + job);
        o[0] = make_float4(acc0[0],acc0[1],acc0[2],acc0[3]);
        o[1] = make_float4(acc0[4],acc0[5],acc0[6],acc0[7]);
        o = reinterpret_cast<float4*>(xhat + (size_t)(s0+2*st+1)*128 + h*64 + job);
        o[0] = make_float4(acc1[0],acc1[1],acc1[2],acc1[3]);
        o[1] = make_float4(acc1[4],acc1[5],acc1[6],acc1[7]);
    }
    rp0 += __shfl_xor(rp0, 1); rp1 += __shfl_xor(rp1, 1);
    rp0 += __shfl_xor(rp0, 2); rp1 += __shfl_xor(rp1, 2);
    rp0 += __shfl_xor(rp0, 4); rp1 += __shfl_xor(rp1, 4);
    if (ot == 0) {
        rec[s0 + 2*st + 0] = rp0 * (1.f/128.f);
        rec[s0 + 2*st + 1] = rp1 * (1.f/128.f);
    }
}

// ---------------------------------------------------------------------------
__global__ void k_scan(const int* __restrict__ counts,
                       int* __restrict__ bases, int* __restrict__ cursors)
{
    if (threadIdx.x == 0) {
        int acc = 0;
        for (int k = 0; k < KC; ++k) { bases[k] = acc; cursors[k] = acc; acc += counts[k]; }
    }
}

__global__ __launch_bounds__(256) void k_scatter(
    const int* __restrict__ cidx, int* __restrict__ cursors, int* __restrict__ seg)
{
    const int s = blockIdx.x * 256 + threadIdx.x;
    const int lane = threadIdx.x & 63;
    const int ci = cidx[s];
    #pragma unroll
    for (int k = 0; k < KC; ++k) {
        const u64 mk = __ballot(ci == k);
        if (ci == k) {
            const int leader = __ffsll(mk) - 1;
            int base = 0;
            if (lane == leader) base = atomicAdd(&cursors[k], (int)__popcll(mk));
            base = __shfl(base, leader, 64);
            seg[base + (int)__popcll(mk & (((u64)1 << lane) - 1))] = s;
        }
    }
}

// k_heads arena (words): HXC[0,2304) z [64][20] then x chunks [64][36];
// HWE[2304,4352) Wh1 chunk; HH1[4352,8704) h1 [64][68];
// HW2[8704,12296) Wh2 [64][56]+pad.  49184 B -> 3 blocks/CU.
#define HXC 0
#define HWE 2304
#define HH1 4352
#define HW2 8704

__global__ __launch_bounds__(256, 3) void k_heads(
    const float* __restrict__ x, const float* __restrict__ zread,
    const float* __restrict__ Wh1, const float* __restrict__ bh1,
    const float* __restrict__ Wh2, const float* __restrict__ bh2,
    const int* __restrict__ counts, const int* __restrict__ bases,
    const int* __restrict__ seg,
    float* __restrict__ surv)
{
    __shared__ float sm[12296];
    __shared__ int idxs[64];
    const int t  = threadIdx.x;
    const int ot = t & 7;
    const int st = t >> 3;
    const int job = ot * 8;

    int k = -1, chunk = 0, pref = 0;
    #pragma unroll
    for (int kk = 0; kk < KC; ++kk) {
        const int ck = (counts[kk] + 63) >> 6;
        if (k < 0) {
            if ((int)blockIdx.x < pref + ck) { k = kk; chunk = (int)blockIdx.x - pref; }
            pref += ck;
        }
    }
    if (k < 0) return;                      // block-uniform, before any barrier
    k     = __builtin_amdgcn_readfirstlane(k);
    chunk = __builtin_amdgcn_readfirstlane(chunk);
    const int cnt  = __builtin_amdgcn_readfirstlane(counts[k]);
    const int base = __builtin_amdgcn_readfirstlane(bases[k]);

    if (t < 64) {
        const int i = chunk*64 + t;
        idxs[t] = seg[base + ((i < cnt) ? i : (cnt - 1))];
    }
    __syncthreads();

    // stage gathered z -> HXC [64][20] ; Wh1 z-rows [16][64] -> HWE
    {
        const int row = t >> 2, c4 = t & 3;
        ST4(HXC + row*20 + c4*4) = *reinterpret_cast<const float4*>(
            &zread[(size_t)idxs[row]*16 + c4*4]);
    }
    {
        const int row = t >> 4, c4 = t & 15;
        ST4(HWE + row*64 + c4*4) = *reinterpret_cast<const float4*>(
            &Wh1[((size_t)k*144 + row)*64 + c4*4]);
    }
    __syncthreads();

    ACC_DECL_INIT(bh1, (size_t)k*64 + job);
    #pragma unroll
    for (int kc = 0; kc < 4; ++kc) K4STEP(kc, HXC, 20, HWE, 64, job);

    for (int c = 0; c < 4; ++c) {
        __syncthreads();
        #pragma unroll
        for (int p = 0; p < 2; ++p) {       // gathered x chunk
            const int g = p * 256 + t, row = g >> 3, c4 = g & 7;
            ST4(HXC + row*36 + c4*4) = *reinterpret_cast<const float4*>(
                &x[(size_t)idxs[row]*128 + c*32 + c4*4]);
        }
        #pragma unroll
        for (int p = 0; p < 2; ++p) {       // Wh1 rows 16+c*32..
            const int g = p * 256 + t, row = g >> 4, c4 = g & 15;
            ST4(HWE + row*64 + c4*4) = *reinterpret_cast<const float4*>(
                &Wh1[((size_t)k*144 + 16 + c*32 + row)*64 + c4*4]);
        }
        __syncthreads();
        #pragma unroll 2
        for (int kc = 0; kc < 8; ++kc) K4STEP(kc, HXC, 36, HWE, 64, job);
    }
    RELU16();
    STORE_LDS_ROWS(HH1, 68, job);

    // stage Wh2 [64][50] zero-padded to [64][56]
    __syncthreads();
    for (int e = t; e < 64*56; e += 256) {
        const int row = e / 56, col = e - row*56;
        sm[HW2 + e] = (col < 50) ? Wh2[((size_t)k*64 + row)*50 + col] : 0.f;
    }
    __syncthreads();
    {
        float acc0[8], acc1[8];
        #pragma unroll
        for (int j = 0; j < 8; ++j) {
            const int col = job + j;
            const float bz = (col < 50) ? bh2[(size_t)k*50 + col] : 0.f;
            acc0[j] = bz; acc1[j] = bz;
        }
        #pragma unroll 2
        for (int kc = 0; kc < 16; ++kc) K4STEP(kc, HH1, 68, HW2, 56, job);

        const bool act0 = (chunk*64 + 2*st + 0) < cnt;
        const bool act1 = (chunk*64 + 2*st + 1) < cnt;
        const int id0 = idxs[2*st + 0], id1 = idxs[2*st + 1];
        #pragma unroll
        for (int j = 0; j < 8; ++j) {
            const int col = job + j;
            if (col < 50) {
                if (act0) surv[(size_t)id0*50 + col] = acc0[j];
                if (act1) surv[(size_t)id1*50 + col] = acc1[j];
            }
        }
    }
}

// ---------------------------------------------------------------------------
extern "C" void kernel_launch(void* const* d_in, const int* in_sizes, int n_in,
                              void* d_out, int out_size, void* d_ws, size_t ws_size,
                              hipStream_t stream)
{
    const float* x   = (const float*)d_in[0];
    const float* We1 = (const float*)d_in[1];
    const float* be1 = (const float*)d_in[2];
    const float* We2 = (const float*)d_in[3];
    const float* be2 = (const float*)d_in[4];
    const float* We3 = (const float*)d_in[5];
    const float* be3 = (const float*)d_in[6];
    const float* Wd1 = (const float*)d_in[7];
    const float* bd1 = (const float*)d_in[8];
    const float* Wd2 = (const float*)d_in[9];
    const float* bd2 = (const float*)d_in[10];
    const float* Wh1 = (const float*)d_in[11];
    const float* bh1 = (const float*)d_in[12];
    const float* Wh2 = (const float*)d_in[13];
    const float* bh2 = (const float*)d_in[14];
    const float* cen = (const float*)d_in[15];
    float* out = (float*)d_out;

    float* out_z  = out;
    float* out_q  = out + (size_t)NS * 16;
    float* out_sv = out + (size_t)NS * 24;
    float* out_xh = out + (size_t)NS * 74;
    float* out_rc = out + (size_t)NS * 202;
    float* out_kl = out + (size_t)NS * 203;

    int* cidx    = (int*)d_ws;       // [NS]
    int* counts  = cidx + NS;        // [8]
    int* bases   = counts + KC;      // [8]
    int* cursors = bases + KC;       // [8]
    int* seg     = cursors + KC;     // [NS]

    hipMemsetAsync(counts, 0, KC * sizeof(int), stream);

    k_enc<<<dim3(NS / 64), dim3(256), 0, stream>>>(
        x, We1, be1, We2, be2, We3, be3, Wd1, bd1, Wd2, bd2, cen,
        out_z, out_q, out_xh, out_rc, out_kl, cidx, counts);

    k_scan<<<dim3(1), dim3(64), 0, stream>>>(counts, bases, cursors);

    k_scatter<<<dim3(NS / 256), dim3(256), 0, stream>>>(cidx, cursors, seg);

    k_heads<<<dim3(NS / 64 + KC), dim3(256), 0, stream>>>(
        x, out_z, Wh1, bh1, Wh2, bh2, counts, bases, seg, out_sv);
}